// Round 1
// baseline (749.326 us; speedup 1.0000x reference)
//
#include <hip/hip_runtime.h>
#include <hip/hip_bf16.h>
#include <cmath>

typedef __attribute__((ext_vector_type(8))) short short8;
typedef __attribute__((ext_vector_type(4))) float f32x4;

#define MFMA16(a, b, c) __builtin_amdgcn_mfma_f32_16x16x32_bf16((a), (b), (c), 0, 0, 0)

static constexpr int BB = 16, NN = 2048, DD = 256, HH = 256;

__device__ inline unsigned short f2bf(float f) {
    union { float f; unsigned int u; } v; v.f = f;
    unsigned int r = v.u + 0x7fffu + ((v.u >> 16) & 1u);
    return (unsigned short)(r >> 16);
}
__device__ inline float bf2f(unsigned short u) {
    union { unsigned int u; float f; } v; v.u = ((unsigned int)u) << 16;
    return v.f;
}
__device__ inline float gelu_exact(float x) {
    return 0.5f * x * (1.0f + erff(x * 0.7071067811865475f));
}

// ---- transpose fp32 [K][N] -> bf16 [N][K] ----
__global__ void transpose_k(const float* __restrict__ src, unsigned short* __restrict__ dst,
                            int K, int N) {
    int tid = blockIdx.x * 256 + threadIdx.x;
    if (tid >= K * N) return;
    int n = tid / K, kk = tid - n * K;
    dst[tid] = f2bf(src[kk * N + n]);
}

// ---- FFN1a: t[p][j] = gelu(x_p*W1a[0][j] + grid_p*W1a[1][j] + b1a[j]) ----
__global__ void ffn1a_k(const float* __restrict__ x, const float* __restrict__ grd,
                        const float* __restrict__ W1a, const float* __restrict__ b1a,
                        unsigned short* __restrict__ t_out) {
    int p = blockIdx.x;
    int j = threadIdx.x;
    float xv = x[p];
    float gv = grd[p & (NN - 1)];
    float v = xv * W1a[j] + gv * W1a[HH + j] + b1a[j];
    t_out[(size_t)p * HH + j] = f2bf(gelu_exact(v));
}

// ---- generic MFMA GEMM: C = A[M,256] @ (BT[N,256])^T, epilogues ----
// EPI 0: +bias, store bf16 (stride 256)
// EPI 1: qkv split, q scaled 1/16, v transposed to [B][D][N]
// EPI 2: +bias, gelu, store bf16 (stride 256)
template <int EPI>
__global__ __launch_bounds__(256) void gemm_k(const unsigned short* __restrict__ A,
                                              const unsigned short* __restrict__ BT,
                                              const float* __restrict__ bias,
                                              unsigned short* __restrict__ out0,
                                              unsigned short* __restrict__ qo,
                                              unsigned short* __restrict__ ko,
                                              unsigned short* __restrict__ vo) {
    int w = threadIdx.x >> 6, lane = threadIdx.x & 63;
    int c = lane & 15, g = lane >> 4;
    int rb = blockIdx.x * 64 + w * 16;
    int cb = blockIdx.y * 64;

    const short8* ap = (const short8*)(A + (size_t)(rb + c) * 256 + g * 8);
    const unsigned short* bp0 = BT + (size_t)(cb + c) * 256 + g * 8;

    f32x4 acc[4];
#pragma unroll
    for (int n = 0; n < 4; n++) acc[n] = (f32x4){0.f, 0.f, 0.f, 0.f};

#pragma unroll
    for (int kc = 0; kc < 8; kc++) {
        short8 a = ap[kc * 4];
#pragma unroll
        for (int n = 0; n < 4; n++) {
            short8 bfr = *(const short8*)(bp0 + (size_t)n * 16 * 256 + kc * 32);
            acc[n] = MFMA16(a, bfr, acc[n]);
        }
    }

#pragma unroll
    for (int n = 0; n < 4; n++) {
        int col = cb + n * 16 + c;
#pragma unroll
        for (int r = 0; r < 4; r++) {
            int row = rb + g * 4 + r;
            float v = acc[n][r];
            if (EPI == 0) {
                out0[(size_t)row * 256 + col] = f2bf(v + bias[col]);
            } else if (EPI == 2) {
                out0[(size_t)row * 256 + col] = f2bf(gelu_exact(v + bias[col]));
            } else {  // qkv
                if (col < 256) {
                    qo[(size_t)row * 256 + col] = f2bf(v * 0.0625f);  // fold 1/sqrt(256)
                } else if (col < 512) {
                    ko[(size_t)row * 256 + (col - 256)] = f2bf(v);
                } else {
                    int bb = row >> 11;
                    int n_in_b = row & (NN - 1);
                    vo[((size_t)(bb * 256 + (col - 512))) * NN + n_in_b] = f2bf(v);
                }
            }
        }
    }
}

// ---- flash attention: 512 blocks (b, qtile64), 4 waves x 16 q-rows ----
__global__ __launch_bounds__(256) void attn_k(const unsigned short* __restrict__ qb,
                                              const unsigned short* __restrict__ kb,
                                              const unsigned short* __restrict__ vTb,
                                              unsigned short* __restrict__ ob) {
    __shared__ float p_lds[4][32 * 17];
    int w = threadIdx.x >> 6, lane = threadIdx.x & 63;
    int c = lane & 15, g = lane >> 4;
    int b = blockIdx.x >> 5;
    int qt = blockIdx.x & 31;
    int qbase = qt * 64 + w * 16;

    // hoist Q fragments (16 rows x 256 k)
    const short8* qp = (const short8*)(qb + (size_t)(b * NN + qbase + c) * DD + g * 8);
    short8 qf[8];
#pragma unroll
    for (int kc = 0; kc < 8; kc++) qf[kc] = qp[kc * 4];

    const unsigned short* kbase = kb + (size_t)(b * NN + c) * DD + g * 8;
    const unsigned short* vbase = vTb + (size_t)(b * DD + c) * NN + g * 8;

    f32x4 oacc[16];
#pragma unroll
    for (int i = 0; i < 16; i++) oacc[i] = (f32x4){0.f, 0.f, 0.f, 0.f};
    float mrun[4] = {-INFINITY, -INFINITY, -INFINITY, -INFINITY};
    float lrun[4] = {0.f, 0.f, 0.f, 0.f};
    float* pl = &p_lds[w][0];

    for (int kt = 0; kt < NN / 32; kt++) {
        // S tile: 16 q x 32 keys
        f32x4 s0 = (f32x4){0.f, 0.f, 0.f, 0.f};
        f32x4 s1 = (f32x4){0.f, 0.f, 0.f, 0.f};
        const unsigned short* kp = kbase + (size_t)kt * 32 * DD;
#pragma unroll
        for (int kc = 0; kc < 8; kc++) {
            short8 k0 = *(const short8*)(kp + kc * 32);
            short8 k1 = *(const short8*)(kp + 16 * DD + kc * 32);
            s0 = MFMA16(qf[kc], k0, s0);
            s1 = MFMA16(qf[kc], k1, s1);
        }
        // online softmax over 32 keys; lane holds rows g*4+r, key c / 16+c
        float tmax[4];
#pragma unroll
        for (int r = 0; r < 4; r++) {
            float t = fmaxf(s0[r], s1[r]);
#pragma unroll
            for (int d = 1; d < 16; d <<= 1) t = fmaxf(t, __shfl_xor(t, d));
            tmax[r] = t;
        }
        bool need = (tmax[0] > mrun[0] + 8.f) || (tmax[1] > mrun[1] + 8.f) ||
                    (tmax[2] > mrun[2] + 8.f) || (tmax[3] > mrun[3] + 8.f);
        float p0[4], p1[4];
        if (__any(need)) {
#pragma unroll
            for (int r = 0; r < 4; r++) {
                float mn = fmaxf(mrun[r], tmax[r]);
                float corr = __expf(mrun[r] - mn);
                p0[r] = __expf(s0[r] - mn);
                p1[r] = __expf(s1[r] - mn);
                float ts = p0[r] + p1[r];
#pragma unroll
                for (int d = 1; d < 16; d <<= 1) ts += __shfl_xor(ts, d);
                lrun[r] = lrun[r] * corr + ts;
                mrun[r] = mn;
#pragma unroll
                for (int nc = 0; nc < 16; nc++) oacc[nc][r] *= corr;
            }
        } else {  // defer-max fast path
#pragma unroll
            for (int r = 0; r < 4; r++) {
                p0[r] = __expf(s0[r] - mrun[r]);
                p1[r] = __expf(s1[r] - mrun[r]);
                float ts = p0[r] + p1[r];
#pragma unroll
                for (int d = 1; d < 16; d <<= 1) ts += __shfl_xor(ts, d);
                lrun[r] += ts;
            }
        }
        // transpose P to A-layout via LDS [key][q], pad 17 (conflict-free both sides)
#pragma unroll
        for (int r = 0; r < 4; r++) {
            pl[c * 17 + g * 4 + r] = p0[r];
            pl[(16 + c) * 17 + g * 4 + r] = p1[r];
        }
        short8 pf;
#pragma unroll
        for (int j = 0; j < 8; j++) {
            float pv = pl[(g * 8 + j) * 17 + c];
            pf[j] = (short)f2bf(pv);
        }
        // PV: O[16q x 256d] += P(16x32) @ V(32x256)
        const unsigned short* vp = vbase + (size_t)kt * 32;
#pragma unroll
        for (int nc = 0; nc < 16; nc++) {
            short8 vf = *(const short8*)(vp + (size_t)nc * 16 * NN);
            oacc[nc] = MFMA16(pf, vf, oacc[nc]);
        }
    }
    // epilogue: normalize and store o bf16
#pragma unroll
    for (int r = 0; r < 4; r++) {
        float inv = 1.f / lrun[r];
        size_t rowoff = (size_t)(b * NN + qbase + g * 4 + r) * DD;
#pragma unroll
        for (int nc = 0; nc < 16; nc++) {
            ob[rowoff + nc * 16 + c] = f2bf(oacc[nc][r] * inv);
        }
    }
}

// ---- mean over N (partial chunks, atomic into bar[b][h]) ----
__global__ void mean_k(const unsigned short* __restrict__ gbuf, float* __restrict__ bar) {
    int b = blockIdx.x, chunk = blockIdx.y, h = threadIdx.x;
    const unsigned short* p = gbuf + ((size_t)(b * NN + chunk * 256) * HH) + h;
    float s = 0.f;
    for (int i = 0; i < 256; i++) s += bf2f(p[(size_t)i * HH]);
    atomicAdd(&bar[b * HH + h], s);
}

// ---- final: out[b][d] = b2b[d] + (1/N) * sum_h bar[b][h] * W2b[h][d] ----
__global__ void final_k(const float* __restrict__ bar, const float* __restrict__ W2b,
                        const float* __restrict__ b2b, float* __restrict__ out) {
    int b = blockIdx.x, d = threadIdx.x;
    float s = 0.f;
    for (int h = 0; h < HH; h++) s += bar[b * HH + h] * W2b[h * DD + d];
    out[b * DD + d] = b2b[d] + s * (1.f / (float)NN);
}

extern "C" void kernel_launch(void* const* d_in, const int* in_sizes, int n_in,
                              void* d_out, int out_size, void* d_ws, size_t ws_size,
                              hipStream_t stream) {
    (void)in_sizes; (void)n_in; (void)out_size; (void)ws_size;
    const float* x    = (const float*)d_in[0];
    const float* grd  = (const float*)d_in[1];
    const float* W1a  = (const float*)d_in[2];
    const float* b1a  = (const float*)d_in[3];
    const float* W1b  = (const float*)d_in[4];
    const float* b1b  = (const float*)d_in[5];
    const float* Wqkv = (const float*)d_in[6];
    const float* W2a  = (const float*)d_in[7];
    const float* b2a  = (const float*)d_in[8];
    const float* W2b  = (const float*)d_in[9];
    const float* b2b  = (const float*)d_in[10];
    float* out = (float*)d_out;

    char* ws = (char*)d_ws;
    const size_t MB = 1024 * 1024;
    unsigned short* t_buf  = (unsigned short*)(ws + 0);        // 16MB (t, reused as o)
    unsigned short* h_buf  = (unsigned short*)(ws + 16 * MB);  // 16MB (h, reused as g)
    unsigned short* q_buf  = (unsigned short*)(ws + 32 * MB);
    unsigned short* k_buf  = (unsigned short*)(ws + 48 * MB);
    unsigned short* vT_buf = (unsigned short*)(ws + 64 * MB);
    unsigned short* W1bT   = (unsigned short*)(ws + 80 * MB);             // 128KB
    unsigned short* WqkvT  = (unsigned short*)(ws + 80 * MB + 512 * 1024);// 384KB
    unsigned short* W2aT   = (unsigned short*)(ws + 81 * MB);             // 128KB
    float*          bar    = (float*)(ws + 81 * MB + 512 * 1024);         // 16KB

    // weight prep
    transpose_k<<<dim3(256), 256, 0, stream>>>(W1b, W1bT, 256, 256);
    transpose_k<<<dim3(768), 256, 0, stream>>>(Wqkv, WqkvT, 256, 768);
    transpose_k<<<dim3(256), 256, 0, stream>>>(W2a, W2aT, 256, 256);
    // FFN1
    ffn1a_k<<<dim3(BB * NN), 256, 0, stream>>>(x, grd, W1a, b1a, t_buf);
    gemm_k<0><<<dim3(512, 4), 256, 0, stream>>>(t_buf, W1bT, b1b, h_buf, nullptr, nullptr, nullptr);
    // qkv
    gemm_k<1><<<dim3(512, 12), 256, 0, stream>>>(h_buf, WqkvT, nullptr, nullptr, q_buf, k_buf, vT_buf);
    // attention -> o (reuses t_buf)
    attn_k<<<dim3(512), 256, 0, stream>>>(q_buf, k_buf, vT_buf, t_buf);
    // FFN2 first layer + gelu -> g (reuses h_buf)
    gemm_k<2><<<dim3(512, 4), 256, 0, stream>>>(t_buf, W2aT, b2a, h_buf, nullptr, nullptr, nullptr);
    // mean over N
    hipMemsetAsync(bar, 0, BB * HH * sizeof(float), stream);
    mean_k<<<dim3(BB, 8), 256, 0, stream>>>(h_buf, bar);
    // final projection
    final_k<<<dim3(BB), 256, 0, stream>>>(bar, W2b, b2b, out);
}

// Round 2
// 637.871 us; speedup vs baseline: 1.1747x; 1.1747x over previous
//
#include <hip/hip_runtime.h>
#include <hip/hip_bf16.h>
#include <cmath>

typedef __attribute__((ext_vector_type(8))) short short8;
typedef __attribute__((ext_vector_type(4))) float f32x4;

#define MFMA16(a, b, c) __builtin_amdgcn_mfma_f32_16x16x32_bf16((a), (b), (c), 0, 0, 0)

static constexpr int BB = 16, NN = 2048, DD = 256, HH = 256;

__device__ inline unsigned short f2bf(float f) {
    union { float f; unsigned int u; } v; v.f = f;
    unsigned int r = v.u + 0x7fffu + ((v.u >> 16) & 1u);
    return (unsigned short)(r >> 16);
}
__device__ inline float bf2f(unsigned short u) {
    union { unsigned int u; float f; } v; v.u = ((unsigned int)u) << 16;
    return v.f;
}
__device__ inline float gelu_exact(float x) {
    return 0.5f * x * (1.0f + erff(x * 0.7071067811865475f));
}
__device__ inline void gload_lds16(const void* g, void* l) {
    __builtin_amdgcn_global_load_lds(
        (const __attribute__((address_space(1))) unsigned int*)g,
        (__attribute__((address_space(3))) unsigned int*)l, 16, 0, 0);
}
__device__ inline void fence_mem() { asm volatile("" ::: "memory"); }

// ---- transpose fp32 [K][N] -> bf16 [N][K] ----
__global__ void transpose_k(const float* __restrict__ src, unsigned short* __restrict__ dst,
                            int K, int N) {
    int tid = blockIdx.x * 256 + threadIdx.x;
    if (tid >= K * N) return;
    int n = tid / K, kk = tid - n * K;
    dst[tid] = f2bf(src[kk * N + n]);
}

// ---- FFN1a ----
__global__ void ffn1a_k(const float* __restrict__ x, const float* __restrict__ grd,
                        const float* __restrict__ W1a, const float* __restrict__ b1a,
                        unsigned short* __restrict__ t_out) {
    int p = blockIdx.x;
    int j = threadIdx.x;
    float xv = x[p];
    float gv = grd[p & (NN - 1)];
    float v = xv * W1a[j] + gv * W1a[HH + j] + b1a[j];
    t_out[(size_t)p * HH + j] = f2bf(gelu_exact(v));
}

// ---- generic MFMA GEMM: C = A[M,256] @ (BT[N,256])^T ----
template <int EPI>
__global__ __launch_bounds__(256) void gemm_k(const unsigned short* __restrict__ A,
                                              const unsigned short* __restrict__ BT,
                                              const float* __restrict__ bias,
                                              unsigned short* __restrict__ out0,
                                              unsigned short* __restrict__ qo,
                                              unsigned short* __restrict__ ko,
                                              unsigned short* __restrict__ vo) {
    int w = threadIdx.x >> 6, lane = threadIdx.x & 63;
    int c = lane & 15, g = lane >> 4;
    int rb = blockIdx.x * 64 + w * 16;
    int cb = blockIdx.y * 64;

    const short8* ap = (const short8*)(A + (size_t)(rb + c) * 256 + g * 8);
    const unsigned short* bp0 = BT + (size_t)(cb + c) * 256 + g * 8;

    f32x4 acc[4];
#pragma unroll
    for (int n = 0; n < 4; n++) acc[n] = (f32x4){0.f, 0.f, 0.f, 0.f};

#pragma unroll
    for (int kc = 0; kc < 8; kc++) {
        short8 a = ap[kc * 4];
#pragma unroll
        for (int n = 0; n < 4; n++) {
            short8 bfr = *(const short8*)(bp0 + (size_t)n * 16 * 256 + kc * 32);
            acc[n] = MFMA16(a, bfr, acc[n]);
        }
    }

#pragma unroll
    for (int n = 0; n < 4; n++) {
        int col = cb + n * 16 + c;
#pragma unroll
        for (int r = 0; r < 4; r++) {
            int row = rb + g * 4 + r;
            float v = acc[n][r];
            if (EPI == 0) {
                out0[(size_t)row * 256 + col] = f2bf(v + bias[col]);
            } else if (EPI == 2) {
                out0[(size_t)row * 256 + col] = f2bf(gelu_exact(v + bias[col]));
            } else {
                if (col < 256) {
                    qo[(size_t)row * 256 + col] = f2bf(v * 0.0625f);
                } else if (col < 512) {
                    ko[(size_t)row * 256 + (col - 256)] = f2bf(v);
                } else {
                    int bb = row >> 11;
                    int n_in_b = row & (NN - 1);
                    vo[((size_t)(bb * 256 + (col - 512))) * NN + n_in_b] = f2bf(v);
                }
            }
        }
    }
}

// ---- flash attention: KVBLK=64, K LDS-staged (swizzled, double-buffered) ----
__global__ __launch_bounds__(256) void attn_k(const unsigned short* __restrict__ qb,
                                              const unsigned short* __restrict__ kb,
                                              const unsigned short* __restrict__ vTb,
                                              unsigned short* __restrict__ ob) {
    __shared__ __attribute__((aligned(16))) char klds[2][64 * 512];  // 64KB swizzled K
    __shared__ float p_lds[4][32 * 17];                              // 8.7KB
    const int tid = threadIdx.x;
    const int w = tid >> 6, lane = tid & 63;
    const int c = lane & 15, g = lane >> 4;
    const int b = blockIdx.x >> 5;
    const int qt = blockIdx.x & 31;
    const int qbase = qt * 64 + w * 16;
    constexpr int NT = NN / 64;  // 32 key-tiles

    // staging lane geometry: instr I=w*8+s covers LDS bytes [I*1024, I*1024+1024)
    const int sl_sub = lane >> 5;          // which of 2 rows in this instr
    const int sl_col = (lane & 31) * 16;   // physical byte col 0..496

    // Q fragments (16 rows x 256) — q already pre-scaled by 1/16
    const short8* qp = (const short8*)(qb + (size_t)(b * NN + qbase + c) * DD + g * 8);
    short8 qf[8];
#pragma unroll
    for (int kc = 0; kc < 8; kc++) qf[kc] = qp[kc * 4];

    const char* kb_bytes = (const char*)kb;
    const int kswz = (c & 7) << 4;  // read-side XOR (row&7 == c&7 since rows = 16t+c)

#define STAGE_K(bufsel, kt_) do {                                                        \
        const char* gsb = kb_bytes + (size_t)(b * NN + (kt_) * 64 + 16 * w) * 512;       \
        _Pragma("unroll")                                                                \
        for (int s_ = 0; s_ < 8; s_++) {                                                 \
            int row_lo = 2 * s_ + sl_sub;                                                \
            int srccol = sl_col ^ ((row_lo & 7) << 4);                                   \
            gload_lds16(gsb + (size_t)row_lo * 512 + srccol,                             \
                        (char*)&klds[bufsel][0] + (w * 8 + s_) * 1024);                  \
        }                                                                                \
    } while (0)

    f32x4 oacc[16];
#pragma unroll
    for (int i = 0; i < 16; i++) oacc[i] = (f32x4){0.f, 0.f, 0.f, 0.f};
    float mrun[4] = {-INFINITY, -INFINITY, -INFINITY, -INFINITY};
    float lrun[4] = {0.f, 0.f, 0.f, 0.f};
    float* pl = &p_lds[w][0];

    STAGE_K(0, 0);

    for (int kt = 0; kt < NT; kt++) {
        int cur = kt & 1;
        if (kt + 1 < NT) {
            STAGE_K(cur ^ 1, kt + 1);
            asm volatile("s_waitcnt vmcnt(8)" ::: "memory");
        } else {
            asm volatile("s_waitcnt vmcnt(0)" ::: "memory");
        }
        __builtin_amdgcn_s_barrier();  // B1: K tile `cur` fully staged
        fence_mem();

        // ---- QK^T: S[16q x 64key] in 4 subtiles ----
        const char* kl = &klds[cur][0];
        f32x4 s[4];
#pragma unroll
        for (int t = 0; t < 4; t++) s[t] = (f32x4){0.f, 0.f, 0.f, 0.f};
        __builtin_amdgcn_s_setprio(1);
#pragma unroll
        for (int kc = 0; kc < 8; kc++) {
            short8 a = qf[kc];
#pragma unroll
            for (int t = 0; t < 4; t++) {
                short8 kf = *(const short8*)(kl + (16 * t + c) * 512 +
                                             ((kc * 64 + g * 16) ^ kswz));
                s[t] = MFMA16(a, kf, s[t]);
            }
        }
        __builtin_amdgcn_s_setprio(0);

        // ---- online softmax over 64 keys ----
        float tmax[4];
#pragma unroll
        for (int r = 0; r < 4; r++) {
            float t0 = fmaxf(fmaxf(s[0][r], s[1][r]), fmaxf(s[2][r], s[3][r]));
#pragma unroll
            for (int d = 1; d < 16; d <<= 1) t0 = fmaxf(t0, __shfl_xor(t0, d));
            tmax[r] = t0;
        }
        bool need = (tmax[0] > mrun[0] + 8.f) || (tmax[1] > mrun[1] + 8.f) ||
                    (tmax[2] > mrun[2] + 8.f) || (tmax[3] > mrun[3] + 8.f);
        if (__any(need)) {
#pragma unroll
            for (int r = 0; r < 4; r++) {
                float mn = fmaxf(mrun[r], tmax[r]);
                float corr = __expf(mrun[r] - mn);
#pragma unroll
                for (int t = 0; t < 4; t++) s[t][r] = __expf(s[t][r] - mn);
                float ts = (s[0][r] + s[1][r]) + (s[2][r] + s[3][r]);
#pragma unroll
                for (int d = 1; d < 16; d <<= 1) ts += __shfl_xor(ts, d);
                lrun[r] = lrun[r] * corr + ts;
                mrun[r] = mn;
#pragma unroll
                for (int nc = 0; nc < 16; nc++) oacc[nc][r] *= corr;
            }
        } else {
#pragma unroll
            for (int r = 0; r < 4; r++) {
#pragma unroll
                for (int t = 0; t < 4; t++) s[t][r] = __expf(s[t][r] - mrun[r]);
                float ts = (s[0][r] + s[1][r]) + (s[2][r] + s[3][r]);
#pragma unroll
                for (int d = 1; d < 16; d <<= 1) ts += __shfl_xor(ts, d);
                lrun[r] += ts;
            }
        }

        // ---- PV per 32-key sub-tile: transpose P via LDS, MFMA with V ----
#pragma unroll
        for (int sub = 0; sub < 2; sub++) {
#pragma unroll
            for (int r = 0; r < 4; r++) {
                pl[c * 17 + g * 4 + r] = s[2 * sub][r];
                pl[(16 + c) * 17 + g * 4 + r] = s[2 * sub + 1][r];
            }
            short8 pf;
#pragma unroll
            for (int j = 0; j < 8; j++) {
                pf[j] = (short)f2bf(pl[(g * 8 + j) * 17 + c]);
            }
            const unsigned short* vp =
                vTb + (size_t)(b * DD + c) * NN + kt * 64 + sub * 32 + g * 8;
            __builtin_amdgcn_s_setprio(1);
#pragma unroll
            for (int nc = 0; nc < 16; nc++) {
                short8 vf = *(const short8*)(vp + (size_t)nc * 16 * NN);
                oacc[nc] = MFMA16(pf, vf, oacc[nc]);
            }
            __builtin_amdgcn_s_setprio(0);
        }

        fence_mem();
        __builtin_amdgcn_s_barrier();  // B2: all waves done reading K tile `cur`
        fence_mem();
    }
#undef STAGE_K

    // epilogue
#pragma unroll
    for (int r = 0; r < 4; r++) {
        float inv = 1.f / lrun[r];
        size_t rowoff = (size_t)(b * NN + qbase + g * 4 + r) * DD;
#pragma unroll
        for (int nc = 0; nc < 16; nc++) {
            ob[rowoff + nc * 16 + c] = f2bf(oacc[nc][r] * inv);
        }
    }
}

// ---- mean over N (vectorized short8 loads) ----
__global__ void mean_k(const unsigned short* __restrict__ gbuf, float* __restrict__ bar) {
    int b = blockIdx.x, chunk = blockIdx.y;
    int t = threadIdx.x;
    int hg = (t & 31) * 8;
    int strip = t >> 5;
    const unsigned short* p =
        gbuf + ((size_t)(b * NN + chunk * 256 + strip * 32) * HH) + hg;
    float s[8] = {0.f, 0.f, 0.f, 0.f, 0.f, 0.f, 0.f, 0.f};
    for (int i = 0; i < 32; i++) {
        short8 v = *(const short8*)(p + (size_t)i * HH);
#pragma unroll
        for (int j = 0; j < 8; j++) s[j] += bf2f((unsigned short)v[j]);
    }
#pragma unroll
    for (int j = 0; j < 8; j++) atomicAdd(&bar[b * HH + hg + j], s[j]);
}

// ---- final projection ----
__global__ void final_k(const float* __restrict__ bar, const float* __restrict__ W2b,
                        const float* __restrict__ b2b, float* __restrict__ out) {
    int b = blockIdx.x, d = threadIdx.x;
    float s = 0.f;
    for (int h = 0; h < HH; h++) s += bar[b * HH + h] * W2b[h * DD + d];
    out[b * DD + d] = b2b[d] + s * (1.f / (float)NN);
}

extern "C" void kernel_launch(void* const* d_in, const int* in_sizes, int n_in,
                              void* d_out, int out_size, void* d_ws, size_t ws_size,
                              hipStream_t stream) {
    (void)in_sizes; (void)n_in; (void)out_size; (void)ws_size;
    const float* x    = (const float*)d_in[0];
    const float* grd  = (const float*)d_in[1];
    const float* W1a  = (const float*)d_in[2];
    const float* b1a  = (const float*)d_in[3];
    const float* W1b  = (const float*)d_in[4];
    const float* b1b  = (const float*)d_in[5];
    const float* Wqkv = (const float*)d_in[6];
    const float* W2a  = (const float*)d_in[7];
    const float* b2a  = (const float*)d_in[8];
    const float* W2b  = (const float*)d_in[9];
    const float* b2b  = (const float*)d_in[10];
    float* out = (float*)d_out;

    char* ws = (char*)d_ws;
    const size_t MB = 1024 * 1024;
    unsigned short* t_buf  = (unsigned short*)(ws + 0);
    unsigned short* h_buf  = (unsigned short*)(ws + 16 * MB);
    unsigned short* q_buf  = (unsigned short*)(ws + 32 * MB);
    unsigned short* k_buf  = (unsigned short*)(ws + 48 * MB);
    unsigned short* vT_buf = (unsigned short*)(ws + 64 * MB);
    unsigned short* W1bT   = (unsigned short*)(ws + 80 * MB);
    unsigned short* WqkvT  = (unsigned short*)(ws + 80 * MB + 512 * 1024);
    unsigned short* W2aT   = (unsigned short*)(ws + 81 * MB);
    float*          bar    = (float*)(ws + 81 * MB + 512 * 1024);

    transpose_k<<<dim3(256), 256, 0, stream>>>(W1b, W1bT, 256, 256);
    transpose_k<<<dim3(768), 256, 0, stream>>>(Wqkv, WqkvT, 256, 768);
    transpose_k<<<dim3(256), 256, 0, stream>>>(W2a, W2aT, 256, 256);
    ffn1a_k<<<dim3(BB * NN), 256, 0, stream>>>(x, grd, W1a, b1a, t_buf);
    gemm_k<0><<<dim3(512, 4), 256, 0, stream>>>(t_buf, W1bT, b1b, h_buf, nullptr, nullptr, nullptr);
    gemm_k<1><<<dim3(512, 12), 256, 0, stream>>>(h_buf, WqkvT, nullptr, nullptr, q_buf, k_buf, vT_buf);
    attn_k<<<dim3(512), 256, 0, stream>>>(q_buf, k_buf, vT_buf, t_buf);
    gemm_k<2><<<dim3(512, 4), 256, 0, stream>>>(t_buf, W2aT, b2a, h_buf, nullptr, nullptr, nullptr);
    hipMemsetAsync(bar, 0, BB * HH * sizeof(float), stream);
    mean_k<<<dim3(BB, 8), 256, 0, stream>>>(h_buf, bar);
    final_k<<<dim3(BB), 256, 0, stream>>>(bar, W2b, b2b, out);
}

// Round 3
// 575.860 us; speedup vs baseline: 1.3012x; 1.1077x over previous
//
#include <hip/hip_runtime.h>
#include <hip/hip_bf16.h>
#include <cmath>

typedef __attribute__((ext_vector_type(8))) short short8;
typedef __attribute__((ext_vector_type(4))) float f32x4;

#define MFMA16(a, b, c) __builtin_amdgcn_mfma_f32_16x16x32_bf16((a), (b), (c), 0, 0, 0)

static constexpr int BB = 16, NN = 2048, DD = 256, HH = 256;

__device__ inline unsigned short f2bf(float f) {
    union { float f; unsigned int u; } v; v.f = f;
    unsigned int r = v.u + 0x7fffu + ((v.u >> 16) & 1u);
    return (unsigned short)(r >> 16);
}
__device__ inline float bf2f(unsigned short u) {
    union { unsigned int u; float f; } v; v.u = ((unsigned int)u) << 16;
    return v.f;
}
__device__ inline float gelu_exact(float x) {
    return 0.5f * x * (1.0f + erff(x * 0.7071067811865475f));
}
__device__ inline void gload_lds16(const void* g, void* l) {
    __builtin_amdgcn_global_load_lds(
        (const __attribute__((address_space(1))) unsigned int*)g,
        (__attribute__((address_space(3))) unsigned int*)l, 16, 0, 0);
}
__device__ inline void fence_mem() { asm volatile("" ::: "memory"); }

// ---- transpose fp32 [K][N] -> bf16 [N][K] ----
__global__ void transpose_k(const float* __restrict__ src, unsigned short* __restrict__ dst,
                            int K, int N) {
    int tid = blockIdx.x * 256 + threadIdx.x;
    if (tid >= K * N) return;
    int n = tid / K, kk = tid - n * K;
    dst[tid] = f2bf(src[kk * N + n]);
}

// ---- FFN1a ----
__global__ void ffn1a_k(const float* __restrict__ x, const float* __restrict__ grd,
                        const float* __restrict__ W1a, const float* __restrict__ b1a,
                        unsigned short* __restrict__ t_out) {
    int p = blockIdx.x;
    int j = threadIdx.x;
    float xv = x[p];
    float gv = grd[p & (NN - 1)];
    float v = xv * W1a[j] + gv * W1a[HH + j] + b1a[j];
    t_out[(size_t)p * HH + j] = f2bf(gelu_exact(v));
}

// ---- generic MFMA GEMM: C = A[M,256] @ (BT[N,256])^T ----
template <int EPI>
__global__ __launch_bounds__(256) void gemm_k(const unsigned short* __restrict__ A,
                                              const unsigned short* __restrict__ BT,
                                              const float* __restrict__ bias,
                                              unsigned short* __restrict__ out0,
                                              unsigned short* __restrict__ qo,
                                              unsigned short* __restrict__ ko,
                                              unsigned short* __restrict__ vo) {
    int w = threadIdx.x >> 6, lane = threadIdx.x & 63;
    int c = lane & 15, g = lane >> 4;
    int rb = blockIdx.x * 64 + w * 16;
    int cb = blockIdx.y * 64;

    const short8* ap = (const short8*)(A + (size_t)(rb + c) * 256 + g * 8);
    const unsigned short* bp0 = BT + (size_t)(cb + c) * 256 + g * 8;

    f32x4 acc[4];
#pragma unroll
    for (int n = 0; n < 4; n++) acc[n] = (f32x4){0.f, 0.f, 0.f, 0.f};

#pragma unroll
    for (int kc = 0; kc < 8; kc++) {
        short8 a = ap[kc * 4];
#pragma unroll
        for (int n = 0; n < 4; n++) {
            short8 bfr = *(const short8*)(bp0 + (size_t)n * 16 * 256 + kc * 32);
            acc[n] = MFMA16(a, bfr, acc[n]);
        }
    }

#pragma unroll
    for (int n = 0; n < 4; n++) {
        int col = cb + n * 16 + c;
#pragma unroll
        for (int r = 0; r < 4; r++) {
            int row = rb + g * 4 + r;
            float v = acc[n][r];
            if (EPI == 0) {
                out0[(size_t)row * 256 + col] = f2bf(v + bias[col]);
            } else if (EPI == 2) {
                out0[(size_t)row * 256 + col] = f2bf(gelu_exact(v + bias[col]));
            } else {
                if (col < 256) {
                    qo[(size_t)row * 256 + col] = f2bf(v * 0.0625f);
                } else if (col < 512) {
                    ko[(size_t)row * 256 + (col - 256)] = f2bf(v);
                } else {
                    int bb = row >> 11;
                    int n_in_b = row & (NN - 1);
                    vo[((size_t)(bb * 256 + (col - 512))) * NN + n_in_b] = f2bf(v);
                }
            }
        }
    }
}

// ---- flash attention: swapped QK^T, in-lane softmax, K LDS dbuf ----
__global__ __launch_bounds__(256) void attn_k(const unsigned short* __restrict__ qb,
                                              const unsigned short* __restrict__ kb,
                                              const unsigned short* __restrict__ vTb,
                                              unsigned short* __restrict__ ob) {
    __shared__ __attribute__((aligned(16))) char klds[2][64 * 512];   // 64KB swizzled K
    __shared__ __attribute__((aligned(16))) unsigned int p_lds[4][16 * 32];  // 8KB bf16 P
    const int tid = threadIdx.x;
    const int w = tid >> 6, lane = tid & 63;
    const int c = lane & 15, g = lane >> 4;
    const int b = blockIdx.x >> 5;
    const int qt = blockIdx.x & 31;
    const int qbase = qt * 64 + w * 16;
    constexpr int NT = NN / 64;  // 32 key-tiles

    // staging lane geometry
    const int sl_sub = lane >> 5;
    const int sl_col = (lane & 31) * 16;

    // Q fragments (16 rows x 256 d) — q pre-scaled by 1/16
    const short8* qp = (const short8*)(qb + (size_t)(b * NN + qbase + c) * DD + g * 8);
    short8 qf[8];
#pragma unroll
    for (int kc = 0; kc < 8; kc++) qf[kc] = qp[kc * 4];

    const char* kb_bytes = (const char*)kb;
    const int kswz = (c & 7) << 4;       // K read-side XOR (row&7 == c&7)
    const int pswz = (c & 7) << 2;       // P dword-index XOR

#define STAGE_K(bufsel, kt_) do {                                                        \
        const char* gsb = kb_bytes + (size_t)(b * NN + (kt_) * 64 + 16 * w) * 512;       \
        _Pragma("unroll")                                                                \
        for (int s_ = 0; s_ < 8; s_++) {                                                 \
            int row_lo = 2 * s_ + sl_sub;                                                \
            int srccol = sl_col ^ ((row_lo & 7) << 4);                                   \
            gload_lds16(gsb + (size_t)row_lo * 512 + srccol,                             \
                        (char*)&klds[bufsel][0] + (w * 8 + s_) * 1024);                  \
        }                                                                                \
    } while (0)

    f32x4 oacc[16];
#pragma unroll
    for (int i = 0; i < 16; i++) oacc[i] = (f32x4){0.f, 0.f, 0.f, 0.f};
    float mrun = -INFINITY;  // running max for q-row c (dup across g-lanes)
    float lrun = 0.f;        // per-lane PARTIAL sum (this lane's 16 keys)
    unsigned int* pl = &p_lds[w][0];

    STAGE_K(0, 0);

    for (int kt = 0; kt < NT; kt++) {
        int cur = kt & 1;
        if (kt + 1 < NT) {
            STAGE_K(cur ^ 1, kt + 1);
            asm volatile("s_waitcnt vmcnt(8)" ::: "memory");
        } else {
            asm volatile("s_waitcnt vmcnt(0)" ::: "memory");
        }
        __builtin_amdgcn_s_barrier();  // B1: K tile `cur` staged
        fence_mem();

        // ---- swapped QK^T: S^T[64key x 16q]; lane holds key=16t+4g+r, q=c ----
        const char* kl = &klds[cur][0];
        f32x4 s[4];
#pragma unroll
        for (int t = 0; t < 4; t++) s[t] = (f32x4){0.f, 0.f, 0.f, 0.f};
        __builtin_amdgcn_s_setprio(1);
#pragma unroll
        for (int kc = 0; kc < 8; kc++) {
            short8 qv = qf[kc];
#pragma unroll
            for (int t = 0; t < 4; t++) {
                short8 kf = *(const short8*)(kl + (16 * t + c) * 512 +
                                             ((kc * 64 + g * 16) ^ kswz));
                s[t] = MFMA16(kf, qv, s[t]);  // swapped: A=K, B=Q
            }
        }
        __builtin_amdgcn_s_setprio(0);
        fence_mem();
        __builtin_amdgcn_s_barrier();  // B2: done reading klds[cur] (early release)
        fence_mem();

        // ---- prefetch V fragments for whole tile (hide L2 latency under softmax) ----
        const unsigned short* vp = vTb + (size_t)(b * DD + c) * NN + kt * 64 + g * 8;
        short8 vf0[16], vf1[16];
#pragma unroll
        for (int nc = 0; nc < 16; nc++) vf0[nc] = *(const short8*)(vp + (size_t)nc * 16 * NN);
#pragma unroll
        for (int nc = 0; nc < 16; nc++) vf1[nc] = *(const short8*)(vp + (size_t)nc * 16 * NN + 32);

        // ---- in-lane softmax over this lane's 16 keys for q=c ----
        float tm[4];
#pragma unroll
        for (int t = 0; t < 4; t++)
            tm[t] = fmaxf(fmaxf(s[t][0], s[t][1]), fmaxf(s[t][2], s[t][3]));
        float tmax = fmaxf(fmaxf(tm[0], tm[1]), fmaxf(tm[2], tm[3]));
        tmax = fmaxf(tmax, __shfl_xor(tmax, 16));
        tmax = fmaxf(tmax, __shfl_xor(tmax, 32));  // row max for q=c

        bool need = tmax > mrun + 8.f;
        if (__any(need)) {
            float mn = fmaxf(mrun, tmax);
            float corr = __expf(mrun - mn);
#pragma unroll
            for (int t = 0; t < 4; t++)
#pragma unroll
                for (int r = 0; r < 4; r++) s[t][r] = __expf(s[t][r] - mn);
            float a0 = (s[0][0] + s[0][1]) + (s[0][2] + s[0][3]);
            float a1 = (s[1][0] + s[1][1]) + (s[1][2] + s[1][3]);
            float a2 = (s[2][0] + s[2][1]) + (s[2][2] + s[2][3]);
            float a3 = (s[3][0] + s[3][1]) + (s[3][2] + s[3][3]);
            lrun = lrun * corr + ((a0 + a1) + (a2 + a3));
            mrun = mn;
            // rescale oacc rows: oacc holds q=4g+r -> fetch corr from lane c'=4g+r
#pragma unroll
            for (int r = 0; r < 4; r++) {
                float cr = __shfl(corr, 4 * g + r + 16 * g);
#pragma unroll
                for (int nc = 0; nc < 16; nc++) oacc[nc][r] *= cr;
            }
        } else {
#pragma unroll
            for (int t = 0; t < 4; t++)
#pragma unroll
                for (int r = 0; r < 4; r++) s[t][r] = __expf(s[t][r] - mrun);
            float a0 = (s[0][0] + s[0][1]) + (s[0][2] + s[0][3]);
            float a1 = (s[1][0] + s[1][1]) + (s[1][2] + s[1][3]);
            float a2 = (s[2][0] + s[2][1]) + (s[2][2] + s[2][3]);
            float a3 = (s[3][0] + s[3][1]) + (s[3][2] + s[3][3]);
            lrun += (a0 + a1) + (a2 + a3);
        }

        // ---- pack P to bf16, write to swizzled LDS [q=c][64 keys] ----
#pragma unroll
        for (int t = 0; t < 4; t++) {
#pragma unroll
            for (int h = 0; h < 2; h++) {
                unsigned int pw = (unsigned int)f2bf(s[t][2 * h]) |
                                  ((unsigned int)f2bf(s[t][2 * h + 1]) << 16);
                pl[c * 32 + ((8 * t + 2 * g + h) ^ pswz)] = pw;
            }
        }
        // read back A-fragments: keys sub*32 + 8g..8g+7 at q=c
        short8 pf0 = *(const short8*)(pl + c * 32 + ((4 * g) ^ pswz));
        short8 pf1 = *(const short8*)(pl + c * 32 + ((16 + 4 * g) ^ pswz));

        // ---- PV: O[16q x 256d] += P @ V ----
        __builtin_amdgcn_s_setprio(1);
#pragma unroll
        for (int nc = 0; nc < 16; nc++) oacc[nc] = MFMA16(pf0, vf0[nc], oacc[nc]);
#pragma unroll
        for (int nc = 0; nc < 16; nc++) oacc[nc] = MFMA16(pf1, vf1[nc], oacc[nc]);
        __builtin_amdgcn_s_setprio(0);
    }
#undef STAGE_K

    // ---- epilogue: reduce l across g-lanes, redistribute, store ----
    float lt = lrun;
    lt += __shfl_xor(lt, 16);
    lt += __shfl_xor(lt, 32);  // total sum for q=c
    float inv_r[4];
#pragma unroll
    for (int r = 0; r < 4; r++) inv_r[r] = 1.f / __shfl(lt, 4 * g + r + 16 * g);
#pragma unroll
    for (int r = 0; r < 4; r++) {
        size_t rowoff = (size_t)(b * NN + qbase + 4 * g + r) * DD;
#pragma unroll
        for (int nc = 0; nc < 16; nc++) {
            ob[rowoff + nc * 16 + c] = f2bf(oacc[nc][r] * inv_r[r]);
        }
    }
}

// ---- mean over N (vectorized short8 loads) ----
__global__ void mean_k(const unsigned short* __restrict__ gbuf, float* __restrict__ bar) {
    int b = blockIdx.x, chunk = blockIdx.y;
    int t = threadIdx.x;
    int hg = (t & 31) * 8;
    int strip = t >> 5;
    const unsigned short* p =
        gbuf + ((size_t)(b * NN + chunk * 256 + strip * 32) * HH) + hg;
    float s[8] = {0.f, 0.f, 0.f, 0.f, 0.f, 0.f, 0.f, 0.f};
    for (int i = 0; i < 32; i++) {
        short8 v = *(const short8*)(p + (size_t)i * HH);
#pragma unroll
        for (int j = 0; j < 8; j++) s[j] += bf2f((unsigned short)v[j]);
    }
#pragma unroll
    for (int j = 0; j < 8; j++) atomicAdd(&bar[b * HH + hg + j], s[j]);
}

// ---- final projection ----
__global__ void final_k(const float* __restrict__ bar, const float* __restrict__ W2b,
                        const float* __restrict__ b2b, float* __restrict__ out) {
    int b = blockIdx.x, d = threadIdx.x;
    float s = 0.f;
    for (int h = 0; h < HH; h++) s += bar[b * HH + h] * W2b[h * DD + d];
    out[b * DD + d] = b2b[d] + s * (1.f / (float)NN);
}

extern "C" void kernel_launch(void* const* d_in, const int* in_sizes, int n_in,
                              void* d_out, int out_size, void* d_ws, size_t ws_size,
                              hipStream_t stream) {
    (void)in_sizes; (void)n_in; (void)out_size; (void)ws_size;
    const float* x    = (const float*)d_in[0];
    const float* grd  = (const float*)d_in[1];
    const float* W1a  = (const float*)d_in[2];
    const float* b1a  = (const float*)d_in[3];
    const float* W1b  = (const float*)d_in[4];
    const float* b1b  = (const float*)d_in[5];
    const float* Wqkv = (const float*)d_in[6];
    const float* W2a  = (const float*)d_in[7];
    const float* b2a  = (const float*)d_in[8];
    const float* W2b  = (const float*)d_in[9];
    const float* b2b  = (const float*)d_in[10];
    float* out = (float*)d_out;

    char* ws = (char*)d_ws;
    const size_t MB = 1024 * 1024;
    unsigned short* t_buf  = (unsigned short*)(ws + 0);
    unsigned short* h_buf  = (unsigned short*)(ws + 16 * MB);
    unsigned short* q_buf  = (unsigned short*)(ws + 32 * MB);
    unsigned short* k_buf  = (unsigned short*)(ws + 48 * MB);
    unsigned short* vT_buf = (unsigned short*)(ws + 64 * MB);
    unsigned short* W1bT   = (unsigned short*)(ws + 80 * MB);
    unsigned short* WqkvT  = (unsigned short*)(ws + 80 * MB + 512 * 1024);
    unsigned short* W2aT   = (unsigned short*)(ws + 81 * MB);
    float*          bar    = (float*)(ws + 81 * MB + 512 * 1024);

    transpose_k<<<dim3(256), 256, 0, stream>>>(W1b, W1bT, 256, 256);
    transpose_k<<<dim3(768), 256, 0, stream>>>(Wqkv, WqkvT, 256, 768);
    transpose_k<<<dim3(256), 256, 0, stream>>>(W2a, W2aT, 256, 256);
    ffn1a_k<<<dim3(BB * NN), 256, 0, stream>>>(x, grd, W1a, b1a, t_buf);
    gemm_k<0><<<dim3(512, 4), 256, 0, stream>>>(t_buf, W1bT, b1b, h_buf, nullptr, nullptr, nullptr);
    gemm_k<1><<<dim3(512, 12), 256, 0, stream>>>(h_buf, WqkvT, nullptr, nullptr, q_buf, k_buf, vT_buf);
    attn_k<<<dim3(512), 256, 0, stream>>>(q_buf, k_buf, vT_buf, t_buf);
    gemm_k<2><<<dim3(512, 4), 256, 0, stream>>>(t_buf, W2aT, b2a, h_buf, nullptr, nullptr, nullptr);
    hipMemsetAsync(bar, 0, BB * HH * sizeof(float), stream);
    mean_k<<<dim3(BB, 8), 256, 0, stream>>>(h_buf, bar);
    final_k<<<dim3(BB), 256, 0, stream>>>(bar, W2b, b2b, out);
}